// Round 19
// baseline (142.156 us; speedup 1.0000x reference)
//
#include <hip/hip_runtime.h>

#define NBATCH 32
#define SEQ    2048
#define NU     512

typedef __attribute__((ext_vector_type(8))) short bf16x8;
typedef __attribute__((ext_vector_type(4))) float f32x4;

__device__ __forceinline__ short bf16_rne(float f) {
  union { float f; unsigned u; } v; v.f = f;
  unsigned r = v.u + 0x7fffu + ((v.u >> 16) & 1u);
  return (short)(r >> 16);
}

__device__ __forceinline__ unsigned pk2(float lo, float hi) {
  return __builtin_amdgcn_perm(__float_as_uint(hi), __float_as_uint(lo), 0x07060302u);
}

__device__ __forceinline__ float fast_tanh(float x) {
  float ax = __builtin_fabsf(x);
  float t  = __expf(-2.0f * ax);
  float r  = (1.0f - t) / (1.0f + t);
  return x < 0.0f ? -r : r;
}

// ---------- fused prep (identical to R17, verified) ----------
// blocks 0..1023: WtSw 8-unit-XOR pre-swizzled transpose (BK=64 tiles)
// blocks 1024..1087: first[b][u] = s_prev[b]@U + U_bias + W_bias
__global__ __launch_bounds__(256) void prep_all(const float* __restrict__ W,
                                                const float* __restrict__ sp,
                                                const float* __restrict__ U,
                                                const float* __restrict__ Ub,
                                                const float* __restrict__ Wb,
                                                short* __restrict__ WtSw,
                                                float* __restrict__ first) {
  __shared__ float srow[NU];
  if (blockIdx.x < 1024) {
    int idx = blockIdx.x * 256 + threadIdx.x;
    int C = idx >> 9, rem = idx & 511;
    int t = rem >> 6, up = (rem >> 3) & 7, e = rem & 7;
    int k = t * 64 + ((up ^ (C & 7)) << 3) + e;
    WtSw[idx] = bf16_rne(W[(size_t)k * NU + C]);
  } else {
    int blk = blockIdx.x - 1024;
    int b = blk >> 1, half = blk & 1, t = threadIdx.x;
    srow[t]       = sp[b * NU + t];
    srow[t + 256] = sp[b * NU + t + 256];
    __syncthreads();
    int col = half * 256 + t;
    float acc = Ub[col] + Wb[col];
    #pragma unroll 8
    for (int k = 0; k < NU; ++k) acc += srow[k] * U[(size_t)k * NU + col];
    first[b * NU + col] = acc;
  }
}

// ---------- main: 8-phase schedule at BM=128/BN=128, 64 KB LDS -> 2 blocks/CU ----------
// 4 waves (2x2), wave tile 64x64, acc[4][4] f32x4 = 64. Per K-tile: 4 quadrant
// phases with af/bq register reuse (16 b128 reads/wave = the 64x64 minimum).
// Two independent barrier groups per CU: one block's MFMA fills the other's waits.
__global__ __launch_bounds__(256, 2) void attn8(
    const float* __restrict__ h,      // (65536, 512) fp32
    const short* __restrict__ WtSw,   // pre-swizzled (512 x 512) bf16
    const float* __restrict__ first,  // (B, 512) incl. U_bias + W_bias
    const float* __restrict__ V,      // (512)
    float* __restrict__ s0)           // (65536) score accumulator (pre-zeroed)
{
  __shared__ short Alds[2][128 * 64];   // 16 KB each, swizzled
  __shared__ short Blds[2][128 * 64];   // 16 KB each, swizzled

  const int tid  = threadIdx.x;
  const int lane = tid & 63;
  const int w    = tid >> 6;            // 0..3
  const int wr   = w >> 1, wc = w & 1;  // 2M x 2N
  const int lr   = lane & 15, hi2 = lane >> 4;

  // XCD remap (R4-proven): 4 col-quarters of a 128-row panel adjacent on one XCD
  const int bid = blockIdx.x;
  const int lb  = (bid & 7) * 256 + (bid >> 3);   // grid 2048 = 8*256, bijective
  const int panel = lb >> 2, q = lb & 3;
  const int rowbase = panel * 128;
  const int b = panel >> 4;

  // ---- A staging: thread -> (row rr, 32-float half uh of the 64-k tile)
  const int rr = tid >> 1, uh = tid & 1;
  const float* hstage = h + (size_t)(rowbase + rr) * NU + uh * 32;
  int wby[4];
  #pragma unroll
  for (int i = 0; i < 4; ++i) {
    int u = uh * 4 + i;
    wby[i] = rr * 128 + ((u ^ (rr & 7)) << 4);
  }

  // ---- B DMA: wave w covers cols w*32..+32; instr i covers cols +i*8
  const short* wsrc = WtSw + (size_t)(q * 128 + w * 32 + (lane >> 3)) * NU + (lane & 7) * 8;

  #define STAGEB(nxt, t1, i2)                                                          \
    {                                                                                  \
      _Pragma("unroll")                                                                \
      for (int i = (i2) * 2; i < (i2) * 2 + 2; ++i)                                    \
        __builtin_amdgcn_global_load_lds(                                              \
            (const __attribute__((address_space(1))) unsigned*)                        \
                (wsrc + (size_t)i * 8 * NU + (t1) * 64),                               \
            (__attribute__((address_space(3))) unsigned*)                              \
                (&Blds[nxt][(w * 32 + i * 8) * 64]), 16, 0, 0);                        \
    }

  // ---- compute-read offsets (bytes)
  int abase[4], bbase[4], s16[2];
  #pragma unroll
  for (int j = 0; j < 4; ++j) abase[j] = (wr * 64 + j * 16 + lr) * 128;
  #pragma unroll
  for (int j = 0; j < 4; ++j) bbase[j] = (wc * 64 + j * 16 + lr) * 128;
  #pragma unroll
  for (int ks = 0; ks < 2; ++ks) s16[ks] = ((ks * 4 + hi2) ^ (lr & 7)) << 4;

  f32x4 acc[4][4];
  #pragma unroll
  for (int mf = 0; mf < 4; ++mf)
    #pragma unroll
    for (int nf = 0; nf < 4; ++nf)
      acc[mf][nf] = (f32x4){0.f, 0.f, 0.f, 0.f};

  float4 ga0, ga1, ga2, ga3;   // A floats 0..15 of this thread's 32
  float4 gb0, gb1, gb2, gb3;   // A floats 16..31

  #define ISSA0(t1)                                                                    \
    { const float* p = hstage + (t1) * 64;                                             \
      ga0 = *reinterpret_cast<const float4*>(p + 0);                                   \
      ga1 = *reinterpret_cast<const float4*>(p + 4);                                   \
      ga2 = *reinterpret_cast<const float4*>(p + 8);                                   \
      ga3 = *reinterpret_cast<const float4*>(p + 12); }
  #define ISSA1(t1)                                                                    \
    { const float* p = hstage + (t1) * 64 + 16;                                        \
      gb0 = *reinterpret_cast<const float4*>(p + 0);                                   \
      gb1 = *reinterpret_cast<const float4*>(p + 4);                                   \
      gb2 = *reinterpret_cast<const float4*>(p + 8);                                   \
      gb3 = *reinterpret_cast<const float4*>(p + 12); }

  #define CVTW0(nxt)                                                                   \
    { char* base = reinterpret_cast<char*>(&Alds[nxt][0]);                             \
      uint4 ua;                                                                        \
      ua.x = pk2(ga0.x, ga0.y); ua.y = pk2(ga0.z, ga0.w);                              \
      ua.z = pk2(ga1.x, ga1.y); ua.w = pk2(ga1.z, ga1.w);                              \
      *reinterpret_cast<uint4*>(base + wby[0]) = ua;                                   \
      ua.x = pk2(ga2.x, ga2.y); ua.y = pk2(ga2.z, ga2.w);                              \
      ua.z = pk2(ga3.x, ga3.y); ua.w = pk2(ga3.z, ga3.w);                              \
      *reinterpret_cast<uint4*>(base + wby[1]) = ua; }
  #define CVTW1(nxt)                                                                   \
    { char* base = reinterpret_cast<char*>(&Alds[nxt][0]);                             \
      uint4 ua;                                                                        \
      ua.x = pk2(gb0.x, gb0.y); ua.y = pk2(gb0.z, gb0.w);                              \
      ua.z = pk2(gb1.x, gb1.y); ua.w = pk2(gb1.z, gb1.w);                              \
      *reinterpret_cast<uint4*>(base + wby[2]) = ua;                                   \
      ua.x = pk2(gb2.x, gb2.y); ua.y = pk2(gb2.z, gb2.w);                              \
      ua.z = pk2(gb3.x, gb3.y); ua.w = pk2(gb3.z, gb3.w);                              \
      *reinterpret_cast<uint4*>(base + wby[3]) = ua; }

  #define READ_A(mh, cur)                                                              \
    _Pragma("unroll")                                                                  \
    for (int mi = 0; mi < 2; ++mi)                                                     \
      _Pragma("unroll")                                                                \
      for (int ks = 0; ks < 2; ++ks)                                                   \
        af[mi][ks] = *reinterpret_cast<const bf16x8*>(                                 \
            reinterpret_cast<const char*>(&Alds[cur][0]) + abase[(mh) * 2 + mi] + s16[ks]);

  #define READ_BQ(BQ, nh, cur)                                                         \
    _Pragma("unroll")                                                                  \
    for (int ni = 0; ni < 2; ++ni)                                                     \
      _Pragma("unroll")                                                                \
      for (int ks = 0; ks < 2; ++ks)                                                   \
        BQ[ni][ks] = *reinterpret_cast<const bf16x8*>(                                 \
            reinterpret_cast<const char*>(&Blds[cur][0]) + bbase[(nh) * 2 + ni] + s16[ks]);

  #define MFMAQ(mh, nh, BQ)                                                            \
    __builtin_amdgcn_s_setprio(1);                                                     \
    _Pragma("unroll")                                                                  \
    for (int ks = 0; ks < 2; ++ks)                                                     \
      _Pragma("unroll")                                                                \
      for (int mi = 0; mi < 2; ++mi)                                                   \
        _Pragma("unroll")                                                              \
        for (int ni = 0; ni < 2; ++ni)                                                 \
          acc[(mh) * 2 + mi][(nh) * 2 + ni] = __builtin_amdgcn_mfma_f32_16x16x32_bf16( \
              af[mi][ks], BQ[ni][ks], acc[(mh) * 2 + mi][(nh) * 2 + ni], 0, 0, 0);     \
    __builtin_amdgcn_s_setprio(0);

  #define BAR                                                                          \
    asm volatile("" ::: "memory");                                                     \
    __builtin_amdgcn_s_barrier();                                                      \
    asm volatile("" ::: "memory");

  // ---- prologue: stage K-tile 0 into buf 0
  ISSA0(0); ISSA1(0);
  STAGEB(0, 0, 0); STAGEB(0, 0, 1);
  CVTW0(0); CVTW1(0);
  asm volatile("s_waitcnt vmcnt(0) lgkmcnt(0)" ::: "memory");
  __builtin_amdgcn_s_barrier();
  asm volatile("" ::: "memory");

  // ---- main loop: K-tiles t = 0..6, staging t+1
  #pragma unroll 1
  for (int t = 0; t < 7; ++t) {
    const int cur = t & 1, nxt = cur ^ 1;
    bf16x8 af[2][2], bq0[2][2], bq1[2][2];
    // p0: reads A(0), B(0); issue A(t+1) first half; DMA B(t+1) instrs 0-1
    READ_A(0, cur); READ_BQ(bq0, 0, cur);
    ISSA0(t + 1);
    STAGEB(nxt, t + 1, 0);
    BAR; MFMAQ(0, 0, bq0); BAR;
    // p1: reads B(1); issue A(t+1) second half; DMA B(t+1) instrs 2-3
    READ_BQ(bq1, 1, cur);
    ISSA1(t + 1);
    STAGEB(nxt, t + 1, 1);
    BAR; MFMAQ(0, 1, bq1); BAR;
    // p2: reads A(1); cvt+write A(t+1) first half; reuse bq0
    READ_A(1, cur);
    CVTW0(nxt);
    BAR; MFMAQ(1, 0, bq0); BAR;
    // p3: cvt+write A(t+1) second half; reuse bq1; boundary drain after MFMA
    CVTW1(nxt);
    BAR; MFMAQ(1, 1, bq1);
    asm volatile("s_waitcnt vmcnt(0) lgkmcnt(0)" ::: "memory");
    BAR;
  }

  // ---- last K-tile (t = 7, buf 1): compute only
  {
    bf16x8 af[2][2], bq0[2][2], bq1[2][2];
    READ_A(0, 1); READ_BQ(bq0, 0, 1);
    BAR; MFMAQ(0, 0, bq0); BAR;
    READ_BQ(bq1, 1, 1);
    BAR; MFMAQ(0, 1, bq1); BAR;
    READ_A(1, 1);
    BAR; MFMAQ(1, 0, bq0); BAR;
    BAR; MFMAQ(1, 1, bq1);
  }

  #undef STAGEB
  #undef ISSA0
  #undef ISSA1
  #undef CVTW0
  #undef CVTW1
  #undef READ_A
  #undef READ_BQ
  #undef MFMAQ
  #undef BAR

  // ---- epilogue: tanh + V, reduce over wave's 64 cols, atomicAdd rows
  float fv[4], vv[4];
  #pragma unroll
  for (int nf = 0; nf < 4; ++nf) {
    int col = q * 128 + wc * 64 + nf * 16 + lr;
    fv[nf] = first[b * NU + col];
    vv[nf] = V[col];
  }
  #pragma unroll
  for (int mf = 0; mf < 4; ++mf) {
    f32x4 p;
    #pragma unroll
    for (int r = 0; r < 4; ++r) {
      float s = 0.f;
      #pragma unroll
      for (int nf = 0; nf < 4; ++nf)
        s += vv[nf] * fast_tanh(fv[nf] + acc[mf][nf][r]);
      p[r] = s;
    }
    #pragma unroll
    for (int m = 1; m < 16; m <<= 1) {
      #pragma unroll
      for (int r = 0; r < 4; ++r) p[r] += __shfl_xor(p[r], m, 64);
    }
    if (lr == 0) {
      const int rbase = rowbase + wr * 64 + mf * 16 + hi2 * 4;
      #pragma unroll
      for (int r = 0; r < 4; ++r) atomicAdd(&s0[rbase + r], p[r]);
    }
  }
}

// ---------- softmax over S per batch (in-place in d_out) + context ----------
__global__ __launch_bounds__(256) void softmax_ctx(const float* __restrict__ sp,
                                                   float* __restrict__ out) {
  const int b = blockIdx.x;
  const int t = threadIdx.x;
  float* wgt = out + NBATCH * NU + (size_t)b * SEQ;
  __shared__ float red[4];

  float v[8];
  float mx = -1e30f;
  #pragma unroll
  for (int i = 0; i < 8; ++i) { v[i] = wgt[t + i * 256]; mx = fmaxf(mx, v[i]); }
  #pragma unroll
  for (int m = 1; m < 64; m <<= 1) mx = fmaxf(mx, __shfl_xor(mx, m, 64));
  if ((t & 63) == 0) red[t >> 6] = mx;
  __syncthreads();
  mx = fmaxf(fmaxf(red[0], red[1]), fmaxf(red[2], red[3]));
  __syncthreads();

  float se = 0.f;
  #pragma unroll
  for (int i = 0; i < 8; ++i) { v[i] = __expf(v[i] - mx); se += v[i]; }
  #pragma unroll
  for (int m = 1; m < 64; m <<= 1) se += __shfl_xor(se, m, 64);
  if ((t & 63) == 0) red[t >> 6] = se;
  __syncthreads();
  se = red[0] + red[1] + red[2] + red[3];
  __syncthreads();

  const float inv = 1.0f / se;
  float sw = 0.f;
  #pragma unroll
  for (int i = 0; i < 8; ++i) { float wi = v[i] * inv; wgt[t + i * 256] = wi; sw += wi; }
  #pragma unroll
  for (int m = 1; m < 64; m <<= 1) sw += __shfl_xor(sw, m, 64);
  if ((t & 63) == 0) red[t >> 6] = sw;
  __syncthreads();
  sw = red[0] + red[1] + red[2] + red[3];

  out[b * NU + t]       = sp[b * NU + t] * sw;
  out[b * NU + t + 256] = sp[b * NU + t + 256] * sw;
}

extern "C" void kernel_launch(void* const* d_in, const int* in_sizes, int n_in,
                              void* d_out, int out_size, void* d_ws, size_t ws_size,
                              hipStream_t stream) {
  (void)in_sizes; (void)n_in; (void)out_size; (void)ws_size;
  const float* s_prev = (const float*)d_in[0];
  const float* h      = (const float*)d_in[1];
  const float* Wk     = (const float*)d_in[2];
  const float* Wb     = (const float*)d_in[3];
  const float* Uk     = (const float*)d_in[4];
  const float* Ub     = (const float*)d_in[5];
  const float* Vk     = (const float*)d_in[6];
  // d_in[7] = V_bias: softmax-shift-invariant, does not affect outputs.

  float* out   = (float*)d_out;
  float* first = (float*)d_ws;                    // 64 KB
  short* WtSw  = (short*)((char*)d_ws + 65536);   // 512 KB
  float* s0    = out + NBATCH * NU;               // score accumulator in weights slot

  hipMemsetAsync(s0, 0, (size_t)NBATCH * SEQ * sizeof(float), stream);
  prep_all   <<<1088, 256, 0, stream>>>(Wk, s_prev, Uk, Ub, Wb, WtSw, first);
  attn8      <<<2048, 256, 0, stream>>>(h, WtSw, first, Vk, s0);
  softmax_ctx<<<  32, 256, 0, stream>>>(s_prev, out);
}

// Round 20
// 133.162 us; speedup vs baseline: 1.0675x; 1.0675x over previous
//
#include <hip/hip_runtime.h>

#define NBATCH 32
#define SEQ    2048
#define NU     512

typedef __attribute__((ext_vector_type(8))) short bf16x8;
typedef __attribute__((ext_vector_type(4))) float f32x4;

__device__ __forceinline__ short bf16_rne(float f) {
  union { float f; unsigned u; } v; v.f = f;
  unsigned r = v.u + 0x7fffu + ((v.u >> 16) & 1u);
  return (short)(r >> 16);
}

__device__ __forceinline__ unsigned pk2(float lo, float hi) {
  return __builtin_amdgcn_perm(__float_as_uint(hi), __float_as_uint(lo), 0x07060302u);
}

__device__ __forceinline__ float fast_tanh(float x) {
  float ax = __builtin_fabsf(x);
  float t  = __expf(-2.0f * ax);
  float r  = (1.0f - t) / (1.0f + t);
  return x < 0.0f ? -r : r;
}

// ---------- fused prep (identical to R17, verified) ----------
__global__ __launch_bounds__(256) void prep_all(const float* __restrict__ W,
                                                const float* __restrict__ sp,
                                                const float* __restrict__ U,
                                                const float* __restrict__ Ub,
                                                const float* __restrict__ Wb,
                                                short* __restrict__ WtSw,
                                                float* __restrict__ first) {
  __shared__ float srow[NU];
  if (blockIdx.x < 1024) {
    int idx = blockIdx.x * 256 + threadIdx.x;
    int C = idx >> 9, rem = idx & 511;
    int t = rem >> 6, up = (rem >> 3) & 7, e = rem & 7;
    int k = t * 64 + ((up ^ (C & 7)) << 3) + e;
    WtSw[idx] = bf16_rne(W[(size_t)k * NU + C]);
  } else {
    int blk = blockIdx.x - 1024;
    int b = blk >> 1, half = blk & 1, t = threadIdx.x;
    srow[t]       = sp[b * NU + t];
    srow[t + 256] = sp[b * NU + t + 256];
    __syncthreads();
    int col = half * 256 + t;
    float acc = Ub[col] + Wb[col];
    #pragma unroll 8
    for (int k = 0; k < NU; ++k) acc += srow[k] * U[(size_t)k * NU + col];
    first[b * NU + col] = acc;
  }
}

// ---------- cvt_h: h fp32 -> hbf bf16, XOR-unit pre-swizzle baked ----------
// hbf[row*512 + tile*64 + u'*8 + e] = bf16(h[row][tile*64 + ((u'^(row&7))<<3) + e])
// Layout contract identical to R17's Alds (stored slot u' holds logical u'^(row&7)),
// so attn8_dma stages LINEARLY via global_load_lds and reads with R17's XOR.
__global__ __launch_bounds__(256) void cvt_h(const float* __restrict__ h,
                                             short* __restrict__ hbf) {
  int idx = blockIdx.x * 256 + threadIdx.x;   // 0..524287 (65536 rows x 8 tiles)
  int row = idx >> 3, tile = idx & 7;
  const float* src = h + (size_t)row * NU + tile * 64;
  short* dst = hbf + (size_t)row * NU + tile * 64;
  const int sw = row & 7;
  #pragma unroll
  for (int up = 0; up < 8; ++up) {
    const float* p = src + ((up ^ sw) << 3);
    float4 x0 = *reinterpret_cast<const float4*>(p);
    float4 x1 = *reinterpret_cast<const float4*>(p + 4);
    uint4 u;
    u.x = pk2(x0.x, x0.y); u.y = pk2(x0.z, x0.w);
    u.z = pk2(x1.x, x1.y); u.w = pk2(x1.z, x1.w);
    *reinterpret_cast<uint4*>(dst + up * 8) = u;
  }
}

// ---------- main (preferred): R17 8-phase, BOTH operands pure global_load_lds ----------
__global__ __launch_bounds__(512, 2) void attn8_dma(
    const short* __restrict__ hbf,    // pre-swizzled bf16 (65536 x 512)
    const short* __restrict__ WtSw,   // pre-swizzled (512 x 512) bf16
    const float* __restrict__ first,
    const float* __restrict__ V,
    float* __restrict__ s0)
{
  __shared__ short Alds[2][256 * 64];
  __shared__ short Blds[2][256 * 64];

  const int tid  = threadIdx.x;
  const int lane = tid & 63;
  const int w    = tid >> 6;
  const int wr   = w >> 2, wc = w & 3;
  const int lr   = lane & 15, hi2 = lane >> 4;

  const int bid = blockIdx.x;
  const int lb  = (bid & 7) * 64 + (bid >> 3);
  const int panel = lb >> 1, half = lb & 1;
  const int rowbase = panel * 256;
  const int b = panel >> 3;

  // A DMA: instr i (0..3): rows (w*4+i)*8 + (lane>>3), unit lane&7 (linear dest)
  const short* asrc = hbf + (size_t)(rowbase + w * 32 + (lane >> 3)) * NU + (lane & 7) * 8;
  // B DMA (R17-verified)
  const short* wsrc = WtSw + (size_t)(half * 256 + w * 8 + (lane >> 3)) * NU + (lane & 7) * 8;

  #define STAGEA(nxt, t1, i2)                                                          \
    {                                                                                  \
      _Pragma("unroll")                                                                \
      for (int i = (i2) * 2; i < (i2) * 2 + 2; ++i)                                    \
        __builtin_amdgcn_global_load_lds(                                              \
            (const __attribute__((address_space(1))) unsigned*)                        \
                (asrc + (size_t)(i * 8) * NU + (t1) * 64),                             \
            (__attribute__((address_space(3))) unsigned*)                              \
                (&Alds[nxt][(w * 4 + i) * 512]), 16, 0, 0);                            \
    }
  #define STAGEB(nxt, t1, bh)                                                          \
    {                                                                                  \
      _Pragma("unroll")                                                                \
      for (int i = 0; i < 2; ++i)                                                      \
        __builtin_amdgcn_global_load_lds(                                              \
            (const __attribute__((address_space(1))) unsigned*)                        \
                (wsrc + (size_t)((bh) * 128 + i * 64) * NU + (t1) * 64),               \
            (__attribute__((address_space(3))) unsigned*)                              \
                (&Blds[nxt][(bh) * 8192 + i * 4096 + w * 512]), 16, 0, 0);             \
    }

  // compute-read offsets (R17-verified)
  int abase[8], bbase[4], s16[2];
  #pragma unroll
  for (int j = 0; j < 8; ++j) abase[j] = (wr * 128 + j * 16 + lr) * 128;
  #pragma unroll
  for (int j = 0; j < 4; ++j) bbase[j] = (wc * 64 + j * 16 + lr) * 128;
  #pragma unroll
  for (int ks = 0; ks < 2; ++ks) s16[ks] = ((ks * 4 + hi2) ^ (lr & 7)) << 4;

  f32x4 acc[8][4];
  #pragma unroll
  for (int mf = 0; mf < 8; ++mf)
    #pragma unroll
    for (int nf = 0; nf < 4; ++nf)
      acc[mf][nf] = (f32x4){0.f, 0.f, 0.f, 0.f};

  #define READ_A(mh, cur)                                                              \
    _Pragma("unroll")                                                                  \
    for (int mi = 0; mi < 4; ++mi)                                                     \
      _Pragma("unroll")                                                                \
      for (int ks = 0; ks < 2; ++ks)                                                   \
        af[mi][ks] = *reinterpret_cast<const bf16x8*>(                                 \
            reinterpret_cast<const char*>(&Alds[cur][0]) + abase[(mh) * 4 + mi] + s16[ks]);
  #define READ_B(nh, cur)                                                              \
    _Pragma("unroll")                                                                  \
    for (int ni = 0; ni < 2; ++ni)                                                     \
      _Pragma("unroll")                                                                \
      for (int ks = 0; ks < 2; ++ks)                                                   \
        bfq[ni][ks] = *reinterpret_cast<const bf16x8*>(                                \
            reinterpret_cast<const char*>(&Blds[cur][0]) + bbase[(nh) * 2 + ni] + s16[ks]);
  #define MFMAQ(mh, nh)                                                                \
    __builtin_amdgcn_s_setprio(1);                                                     \
    _Pragma("unroll")                                                                  \
    for (int ks = 0; ks < 2; ++ks)                                                     \
      _Pragma("unroll")                                                                \
      for (int mi = 0; mi < 4; ++mi)                                                   \
        _Pragma("unroll")                                                              \
        for (int ni = 0; ni < 2; ++ni)                                                 \
          acc[(mh) * 4 + mi][(nh) * 2 + ni] = __builtin_amdgcn_mfma_f32_16x16x32_bf16( \
              af[mi][ks], bfq[ni][ks], acc[(mh) * 4 + mi][(nh) * 2 + ni], 0, 0, 0);    \
    __builtin_amdgcn_s_setprio(0);
  #define BAR                                                                          \
    asm volatile("" ::: "memory");                                                     \
    __builtin_amdgcn_s_barrier();                                                      \
    asm volatile("" ::: "memory");

  // ---- prologue: DMA K-tile 0 (8 instrs), drain, barrier
  STAGEA(0, 0, 0); STAGEA(0, 0, 1);
  STAGEB(0, 0, 0); STAGEB(0, 0, 1);
  asm volatile("s_waitcnt vmcnt(0) lgkmcnt(0)" ::: "memory");
  __builtin_amdgcn_s_barrier();
  asm volatile("" ::: "memory");

  // ---- main loop: K-tiles t = 0..6, staging t+1 entirely in p0/p1
  #pragma unroll 1
  for (int t = 0; t < 7; ++t) {
    const int cur = t & 1, nxt = cur ^ 1;
    bf16x8 af[4][2], bfq[2][2];
    // p0: A-half0 DMA + B-half0 DMA
    READ_A(0, cur); READ_B(0, cur);
    STAGEA(nxt, t + 1, 0);
    STAGEB(nxt, t + 1, 0);
    BAR; MFMAQ(0, 0); BAR;
    // p1: A-half1 DMA + B-half1 DMA
    READ_B(1, cur);
    STAGEA(nxt, t + 1, 1);
    STAGEB(nxt, t + 1, 1);
    BAR; MFMAQ(0, 1); BAR;
    // p2
    READ_A(1, cur); READ_B(0, cur);
    BAR; MFMAQ(1, 0); BAR;
    // p3: boundary drain after MFMA (DMAs 2+ phases old)
    READ_B(1, cur);
    BAR; MFMAQ(1, 1);
    asm volatile("s_waitcnt vmcnt(0) lgkmcnt(0)" ::: "memory");
    BAR;
  }

  // ---- last K-tile (t = 7, buf 1)
  {
    bf16x8 af[4][2], bfq[2][2];
    READ_A(0, 1); READ_B(0, 1);
    BAR; MFMAQ(0, 0); BAR;
    READ_B(1, 1);
    BAR; MFMAQ(0, 1); BAR;
    READ_A(1, 1); READ_B(0, 1);
    BAR; MFMAQ(1, 0); BAR;
    READ_B(1, 1);
    BAR; MFMAQ(1, 1);
  }

  #undef STAGEA
  #undef STAGEB
  #undef READ_A
  #undef READ_B
  #undef MFMAQ
  #undef BAR

  // ---- epilogue (R17-verified)
  float fv[4], vv[4];
  #pragma unroll
  for (int nf = 0; nf < 4; ++nf) {
    int col = half * 256 + wc * 64 + nf * 16 + lr;
    fv[nf] = first[b * NU + col];
    vv[nf] = V[col];
  }
  #pragma unroll
  for (int mf = 0; mf < 8; ++mf) {
    f32x4 p;
    #pragma unroll
    for (int r = 0; r < 4; ++r) {
      float s = 0.f;
      #pragma unroll
      for (int nf = 0; nf < 4; ++nf)
        s += vv[nf] * fast_tanh(fv[nf] + acc[mf][nf][r]);
      p[r] = s;
    }
    #pragma unroll
    for (int m = 1; m < 16; m <<= 1) {
      #pragma unroll
      for (int r = 0; r < 4; ++r) p[r] += __shfl_xor(p[r], m, 64);
    }
    if (lr == 0) {
      const int rbase = rowbase + wr * 128 + mf * 16 + hi2 * 4;
      #pragma unroll
      for (int r = 0; r < 4; ++r) atomicAdd(&s0[rbase + r], p[r]);
    }
  }
}

// ---------- fallback main (exact R17 champion, reg-staged A) ----------
__global__ __launch_bounds__(512, 2) void attn8(
    const float* __restrict__ h,
    const short* __restrict__ WtSw,
    const float* __restrict__ first,
    const float* __restrict__ V,
    float* __restrict__ s0)
{
  __shared__ short Alds[2][256 * 64];
  __shared__ short Blds[2][256 * 64];

  const int tid  = threadIdx.x;
  const int lane = tid & 63;
  const int w    = tid >> 6;
  const int wr   = w >> 2, wc = w & 3;
  const int lr   = lane & 15, hi2 = lane >> 4;

  const int bid = blockIdx.x;
  const int lb  = (bid & 7) * 64 + (bid >> 3);
  const int panel = lb >> 1, half = lb & 1;
  const int rowbase = panel * 256;
  const int b = panel >> 3;

  const float* hstage = h + (size_t)(rowbase + (tid >> 2)) * NU + (tid & 3) * 16;
  const int rr = tid >> 2, u0 = (tid & 3) * 2;
  const int wby0 = rr * 128 + ((u0 ^ (rr & 7)) << 4);
  const int wby1 = rr * 128 + (((u0 | 1) ^ (rr & 7)) << 4);
  const short* wsrc = WtSw + (size_t)(half * 256 + w * 8 + (lane >> 3)) * NU + (lane & 7) * 8;

  int abase[8], bbase[4], s16[2];
  #pragma unroll
  for (int j = 0; j < 8; ++j) abase[j] = (wr * 128 + j * 16 + lr) * 128;
  #pragma unroll
  for (int j = 0; j < 4; ++j) bbase[j] = (wc * 64 + j * 16 + lr) * 128;
  #pragma unroll
  for (int ks = 0; ks < 2; ++ks) s16[ks] = ((ks * 4 + hi2) ^ (lr & 7)) << 4;

  f32x4 acc[8][4];
  #pragma unroll
  for (int mf = 0; mf < 8; ++mf)
    #pragma unroll
    for (int nf = 0; nf < 4; ++nf)
      acc[mf][nf] = (f32x4){0.f, 0.f, 0.f, 0.f};

  float4 ga0, ga1, ga2, ga3;
  float4 gb0, gb1, gb2, gb3;

  #define STAGEB(nxt, t1, bh)                                                          \
    {                                                                                  \
      _Pragma("unroll")                                                                \
      for (int i = 0; i < 2; ++i)                                                      \
        __builtin_amdgcn_global_load_lds(                                              \
            (const __attribute__((address_space(1))) unsigned*)                        \
                (wsrc + (size_t)((bh) * 128 + i * 64) * NU + (t1) * 64),               \
            (__attribute__((address_space(3))) unsigned*)                              \
                (&Blds[nxt][(bh) * 8192 + i * 4096 + w * 512]), 16, 0, 0);             \
    }
  #define ISSA(G0, G1, G2, G3, t1, ah)                                                 \
    {                                                                                  \
      const float* p = hstage + (size_t)(ah) * 128 * NU + (t1) * 64;                   \
      G0 = *reinterpret_cast<const float4*>(p + 0);                                    \
      G1 = *reinterpret_cast<const float4*>(p + 4);                                    \
      G2 = *reinterpret_cast<const float4*>(p + 8);                                    \
      G3 = *reinterpret_cast<const float4*>(p + 12);                                   \
    }
  #define CVTW(nxt, ah, G0, G1, G2, G3)                                                \
    {                                                                                  \
      char* base = reinterpret_cast<char*>(&Alds[nxt][0]) + (ah) * 16384;              \
      uint4 ua, ub;                                                                    \
      ua.x = pk2(G0.x, G0.y); ua.y = pk2(G0.z, G0.w);                                  \
      ua.z = pk2(G1.x, G1.y); ua.w = pk2(G1.z, G1.w);                                  \
      ub.x = pk2(G2.x, G2.y); ub.y = pk2(G2.z, G2.w);                                  \
      ub.z = pk2(G3.x, G3.y); ub.w = pk2(G3.z, G3.w);                                  \
      *reinterpret_cast<uint4*>(base + wby0) = ua;                                     \
      *reinterpret_cast<uint4*>(base + wby1) = ub;                                     \
    }
  #define READ_A(mh, cur)                                                              \
    _Pragma("unroll")                                                                  \
    for (int mi = 0; mi < 4; ++mi)                                                     \
      _Pragma("unroll")                                                                \
      for (int ks = 0; ks < 2; ++ks)                                                   \
        af[mi][ks] = *reinterpret_cast<const bf16x8*>(                                 \
            reinterpret_cast<const char*>(&Alds[cur][0]) + abase[(mh) * 4 + mi] + s16[ks]);
  #define READ_B(nh, cur)                                                              \
    _Pragma("unroll")                                                                  \
    for (int ni = 0; ni < 2; ++ni)                                                     \
      _Pragma("unroll")                                                                \
      for (int ks = 0; ks < 2; ++ks)                                                   \
        bfq[ni][ks] = *reinterpret_cast<const bf16x8*>(                                \
            reinterpret_cast<const char*>(&Blds[cur][0]) + bbase[(nh) * 2 + ni] + s16[ks]);
  #define MFMAQ(mh, nh)                                                                \
    __builtin_amdgcn_s_setprio(1);                                                     \
    _Pragma("unroll")                                                                  \
    for (int ks = 0; ks < 2; ++ks)                                                     \
      _Pragma("unroll")                                                                \
      for (int mi = 0; mi < 4; ++mi)                                                   \
        _Pragma("unroll")                                                              \
        for (int ni = 0; ni < 2; ++ni)                                                 \
          acc[(mh) * 4 + mi][(nh) * 2 + ni] = __builtin_amdgcn_mfma_f32_16x16x32_bf16( \
              af[mi][ks], bfq[ni][ks], acc[(mh) * 4 + mi][(nh) * 2 + ni], 0, 0, 0);    \
    __builtin_amdgcn_s_setprio(0);
  #define BAR                                                                          \
    asm volatile("" ::: "memory");                                                     \
    __builtin_amdgcn_s_barrier();                                                      \
    asm volatile("" ::: "memory");

  STAGEB(0, 0, 0); STAGEB(0, 0, 1);
  ISSA(ga0, ga1, ga2, ga3, 0, 0);
  CVTW(0, 0, ga0, ga1, ga2, ga3);
  ISSA(gb0, gb1, gb2, gb3, 0, 1);
  CVTW(0, 1, gb0, gb1, gb2, gb3);
  asm volatile("s_waitcnt vmcnt(0) lgkmcnt(0)" ::: "memory");
  __builtin_amdgcn_s_barrier();
  asm volatile("" ::: "memory");

  #pragma unroll 1
  for (int t = 0; t < 7; ++t) {
    const int cur = t & 1, nxt = cur ^ 1;
    bf16x8 af[4][2], bfq[2][2];
    READ_A(0, cur); READ_B(0, cur);
    STAGEB(nxt, t + 1, 0);
    ISSA(ga0, ga1, ga2, ga3, t + 1, 0);
    BAR; MFMAQ(0, 0); BAR;
    READ_B(1, cur);
    STAGEB(nxt, t + 1, 1);
    ISSA(gb0, gb1, gb2, gb3, t + 1, 1);
    BAR; MFMAQ(0, 1); BAR;
    READ_A(1, cur); READ_B(0, cur);
    CVTW(nxt, 0, ga0, ga1, ga2, ga3);
    BAR; MFMAQ(1, 0); BAR;
    READ_B(1, cur);
    CVTW(nxt, 1, gb0, gb1, gb2, gb3);
    BAR; MFMAQ(1, 1);
    asm volatile("s_waitcnt vmcnt(0) lgkmcnt(0)" ::: "memory");
    BAR;
  }
  {
    bf16x8 af[4][2], bfq[2][2];
    READ_A(0, 1); READ_B(0, 1);
    BAR; MFMAQ(0, 0); BAR;
    READ_B(1, 1);
    BAR; MFMAQ(0, 1); BAR;
    READ_A(1, 1); READ_B(0, 1);
    BAR; MFMAQ(1, 0); BAR;
    READ_B(1, 1);
    BAR; MFMAQ(1, 1);
  }

  #undef STAGEB
  #undef ISSA
  #undef CVTW
  #undef READ_A
  #undef READ_B
  #undef MFMAQ
  #undef BAR

  float fv[4], vv[4];
  #pragma unroll
  for (int nf = 0; nf < 4; ++nf) {
    int col = half * 256 + wc * 64 + nf * 16 + lr;
    fv[nf] = first[b * NU + col];
    vv[nf] = V[col];
  }
  #pragma unroll
  for (int mf = 0; mf < 8; ++mf) {
    f32x4 p;
    #pragma unroll
    for (int r = 0; r < 4; ++r) {
      float s = 0.f;
      #pragma unroll
      for (int nf = 0; nf < 4; ++nf)
        s += vv[nf] * fast_tanh(fv[nf] + acc[mf][nf][r]);
      p[r] = s;
    }
    #pragma unroll
    for (int m = 1; m < 16; m <<= 1) {
      #pragma unroll
      for (int r = 0; r < 4; ++r) p[r] += __shfl_xor(p[r], m, 64);
    }
    if (lr == 0) {
      const int rbase = rowbase + wr * 128 + mf * 16 + hi2 * 4;
      #pragma unroll
      for (int r = 0; r < 4; ++r) atomicAdd(&s0[rbase + r], p[r]);
    }
  }
}

// ---------- softmax over S per batch (in-place in d_out) + context ----------
__global__ __launch_bounds__(256) void softmax_ctx(const float* __restrict__ sp,
                                                   float* __restrict__ out) {
  const int b = blockIdx.x;
  const int t = threadIdx.x;
  float* wgt = out + NBATCH * NU + (size_t)b * SEQ;
  __shared__ float red[4];

  float v[8];
  float mx = -1e30f;
  #pragma unroll
  for (int i = 0; i < 8; ++i) { v[i] = wgt[t + i * 256]; mx = fmaxf(mx, v[i]); }
  #pragma unroll
  for (int m = 1; m < 64; m <<= 1) mx = fmaxf(mx, __shfl_xor(mx, m, 64));
  if ((t & 63) == 0) red[t >> 6] = mx;
  __syncthreads();
  mx = fmaxf(fmaxf(red[0], red[1]), fmaxf(red[2], red[3]));
  __syncthreads();

  float se = 0.f;
  #pragma unroll
  for (int i = 0; i < 8; ++i) { v[i] = __expf(v[i] - mx); se += v[i]; }
  #pragma unroll
  for (int m = 1; m < 64; m <<= 1) se += __shfl_xor(se, m, 64);
  if ((t & 63) == 0) red[t >> 6] = se;
  __syncthreads();
  se = red[0] + red[1] + red[2] + red[3];
  __syncthreads();

  const float inv = 1.0f / se;
  float sw = 0.f;
  #pragma unroll
  for (int i = 0; i < 8; ++i) { float wi = v[i] * inv; wgt[t + i * 256] = wi; sw += wi; }
  #pragma unroll
  for (int m = 1; m < 64; m <<= 1) sw += __shfl_xor(sw, m, 64);
  if ((t & 63) == 0) red[t >> 6] = sw;
  __syncthreads();
  sw = red[0] + red[1] + red[2] + red[3];

  out[b * NU + t]       = sp[b * NU + t] * sw;
  out[b * NU + t + 256] = sp[b * NU + t + 256] * sw;
}

extern "C" void kernel_launch(void* const* d_in, const int* in_sizes, int n_in,
                              void* d_out, int out_size, void* d_ws, size_t ws_size,
                              hipStream_t stream) {
  (void)in_sizes; (void)n_in; (void)out_size;
  const float* s_prev = (const float*)d_in[0];
  const float* h      = (const float*)d_in[1];
  const float* Wk     = (const float*)d_in[2];
  const float* Wb     = (const float*)d_in[3];
  const float* Uk     = (const float*)d_in[4];
  const float* Ub     = (const float*)d_in[5];
  const float* Vk     = (const float*)d_in[6];
  // d_in[7] = V_bias: softmax-shift-invariant, does not affect outputs.

  float* out   = (float*)d_out;
  float* first = (float*)d_ws;                    // 64 KB
  short* WtSw  = (short*)((char*)d_ws + 65536);   // 512 KB
  short* hbf   = (short*)((char*)d_ws + (1 << 20));  // 64 MB (if ws permits)
  float* s0    = out + NBATCH * NU;

  const size_t need = (size_t)(1 << 20) + (size_t)65536 * NU * sizeof(short);

  hipMemsetAsync(s0, 0, (size_t)NBATCH * SEQ * sizeof(float), stream);
  prep_all<<<1088, 256, 0, stream>>>(Wk, s_prev, Uk, Ub, Wb, WtSw, first);
  if (ws_size >= need) {
    cvt_h    <<<2048, 256, 0, stream>>>(h, hbf);
    attn8_dma<<< 512, 512, 0, stream>>>(hbf, WtSw, first, Vk, s0);
  } else {
    attn8    <<< 512, 512, 0, stream>>>(h, WtSw, first, Vk, s0);
  }
  softmax_ctx<<<32, 256, 0, stream>>>(s_prev, out);
}

// Round 21
// 112.818 us; speedup vs baseline: 1.2600x; 1.1803x over previous
//
#include <hip/hip_runtime.h>

#define NBATCH 32
#define SEQ    2048
#define NU     512

typedef __attribute__((ext_vector_type(8))) short bf16x8;
typedef __attribute__((ext_vector_type(4))) float f32x4;

__device__ __forceinline__ short bf16_rne(float f) {
  union { float f; unsigned u; } v; v.f = f;
  unsigned r = v.u + 0x7fffu + ((v.u >> 16) & 1u);
  return (short)(r >> 16);
}

__device__ __forceinline__ unsigned pk2(float lo, float hi) {
  return __builtin_amdgcn_perm(__float_as_uint(hi), __float_as_uint(lo), 0x07060302u);
}

__device__ __forceinline__ float fast_tanh(float x) {
  float ax = __builtin_fabsf(x);
  float t  = __expf(-2.0f * ax);
  float r  = (1.0f - t) / (1.0f + t);
  return x < 0.0f ? -r : r;
}

// ---------- fused prep + cvt ----------
// blocks 0..1023:    WtSw 8-unit-XOR pre-swizzled transpose (R17-verified)
// blocks 1024..1087: first[b][u] = s_prev[b]@U + U_bias + W_bias (verified)
// blocks 1088..3135: h fp32 -> hbf bf16, XOR-unit pre-swizzle baked, LANE-MAJOR:
//   one wave per row; lane l stores 16B at hbf[row*512 + l*8] (wave store = 1 KB
//   contiguous); reads the permuted unit (tile = l>>3, up = l&7):
//   koff = tile*64 + ((up ^ (row&7))<<3). Same layout contract as R20 (verified).
__global__ __launch_bounds__(256) void prep_cvt(const float* __restrict__ W,
                                                const float* __restrict__ sp,
                                                const float* __restrict__ U,
                                                const float* __restrict__ Ub,
                                                const float* __restrict__ Wb,
                                                const float* __restrict__ h,
                                                short* __restrict__ WtSw,
                                                float* __restrict__ first,
                                                short* __restrict__ hbf) {
  __shared__ float srow[NU];
  if (blockIdx.x < 1024) {
    int idx = blockIdx.x * 256 + threadIdx.x;
    int C = idx >> 9, rem = idx & 511;
    int t = rem >> 6, up = (rem >> 3) & 7, e = rem & 7;
    int k = t * 64 + ((up ^ (C & 7)) << 3) + e;
    WtSw[idx] = bf16_rne(W[(size_t)k * NU + C]);
  } else if (blockIdx.x < 1088) {
    int blk = blockIdx.x - 1024;
    int b = blk >> 1, half = blk & 1, t = threadIdx.x;
    srow[t]       = sp[b * NU + t];
    srow[t + 256] = sp[b * NU + t + 256];
    __syncthreads();
    int col = half * 256 + t;
    float acc = Ub[col] + Wb[col];
    #pragma unroll 8
    for (int k = 0; k < NU; ++k) acc += srow[k] * U[(size_t)k * NU + col];
    first[b * NU + col] = acc;
  } else {
    // cvt: 2048 blocks x 4 waves = 8192 waves; 8 rows per wave
    const int gw = (blockIdx.x - 1088) * 4 + (threadIdx.x >> 6);
    const int l  = threadIdx.x & 63;
    const int tile = l >> 3, up = l & 7;
    #pragma unroll
    for (int i = 0; i < 8; ++i) {
      const int r = gw * 8 + i;
      const int koff = tile * 64 + ((up ^ (r & 7)) << 3);
      const float* p = h + (size_t)r * NU + koff;
      float4 x0 = *reinterpret_cast<const float4*>(p);
      float4 x1 = *reinterpret_cast<const float4*>(p + 4);
      uint4 u;
      u.x = pk2(x0.x, x0.y); u.y = pk2(x0.z, x0.w);
      u.z = pk2(x1.x, x1.y); u.w = pk2(x1.z, x1.w);
      *reinterpret_cast<uint4*>(hbf + (size_t)r * NU + l * 8) = u;
    }
  }
}

// ---------- main (preferred): 8-phase, BOTH operands pure global_load_lds (R20-verified) ----------
__global__ __launch_bounds__(512, 2) void attn8_dma(
    const short* __restrict__ hbf,    // pre-swizzled bf16 (65536 x 512)
    const short* __restrict__ WtSw,   // pre-swizzled (512 x 512) bf16
    const float* __restrict__ first,
    const float* __restrict__ V,
    float* __restrict__ s0)
{
  __shared__ short Alds[2][256 * 64];
  __shared__ short Blds[2][256 * 64];

  const int tid  = threadIdx.x;
  const int lane = tid & 63;
  const int w    = tid >> 6;
  const int wr   = w >> 2, wc = w & 3;
  const int lr   = lane & 15, hi2 = lane >> 4;

  const int bid = blockIdx.x;
  const int lb  = (bid & 7) * 64 + (bid >> 3);
  const int panel = lb >> 1, half = lb & 1;
  const int rowbase = panel * 256;
  const int b = panel >> 3;

  const short* asrc = hbf + (size_t)(rowbase + w * 32 + (lane >> 3)) * NU + (lane & 7) * 8;
  const short* wsrc = WtSw + (size_t)(half * 256 + w * 8 + (lane >> 3)) * NU + (lane & 7) * 8;

  #define STAGEA(nxt, t1, i2)                                                          \
    {                                                                                  \
      _Pragma("unroll")                                                                \
      for (int i = (i2) * 2; i < (i2) * 2 + 2; ++i)                                    \
        __builtin_amdgcn_global_load_lds(                                              \
            (const __attribute__((address_space(1))) unsigned*)                        \
                (asrc + (size_t)(i * 8) * NU + (t1) * 64),                             \
            (__attribute__((address_space(3))) unsigned*)                              \
                (&Alds[nxt][(w * 4 + i) * 512]), 16, 0, 0);                            \
    }
  #define STAGEB(nxt, t1, bh)                                                          \
    {                                                                                  \
      _Pragma("unroll")                                                                \
      for (int i = 0; i < 2; ++i)                                                      \
        __builtin_amdgcn_global_load_lds(                                              \
            (const __attribute__((address_space(1))) unsigned*)                        \
                (wsrc + (size_t)((bh) * 128 + i * 64) * NU + (t1) * 64),               \
            (__attribute__((address_space(3))) unsigned*)                              \
                (&Blds[nxt][(bh) * 8192 + i * 4096 + w * 512]), 16, 0, 0);             \
    }

  int abase[8], bbase[4], s16[2];
  #pragma unroll
  for (int j = 0; j < 8; ++j) abase[j] = (wr * 128 + j * 16 + lr) * 128;
  #pragma unroll
  for (int j = 0; j < 4; ++j) bbase[j] = (wc * 64 + j * 16 + lr) * 128;
  #pragma unroll
  for (int ks = 0; ks < 2; ++ks) s16[ks] = ((ks * 4 + hi2) ^ (lr & 7)) << 4;

  f32x4 acc[8][4];
  #pragma unroll
  for (int mf = 0; mf < 8; ++mf)
    #pragma unroll
    for (int nf = 0; nf < 4; ++nf)
      acc[mf][nf] = (f32x4){0.f, 0.f, 0.f, 0.f};

  #define READ_A(mh, cur)                                                              \
    _Pragma("unroll")                                                                  \
    for (int mi = 0; mi < 4; ++mi)                                                     \
      _Pragma("unroll")                                                                \
      for (int ks = 0; ks < 2; ++ks)                                                   \
        af[mi][ks] = *reinterpret_cast<const bf16x8*>(                                 \
            reinterpret_cast<const char*>(&Alds[cur][0]) + abase[(mh) * 4 + mi] + s16[ks]);
  #define READ_B(nh, cur)                                                              \
    _Pragma("unroll")                                                                  \
    for (int ni = 0; ni < 2; ++ni)                                                     \
      _Pragma("unroll")                                                                \
      for (int ks = 0; ks < 2; ++ks)                                                   \
        bfq[ni][ks] = *reinterpret_cast<const bf16x8*>(                                \
            reinterpret_cast<const char*>(&Blds[cur][0]) + bbase[(nh) * 2 + ni] + s16[ks]);
  #define MFMAQ(mh, nh)                                                                \
    __builtin_amdgcn_s_setprio(1);                                                     \
    _Pragma("unroll")                                                                  \
    for (int ks = 0; ks < 2; ++ks)                                                     \
      _Pragma("unroll")                                                                \
      for (int mi = 0; mi < 4; ++mi)                                                   \
        _Pragma("unroll")                                                              \
        for (int ni = 0; ni < 2; ++ni)                                                 \
          acc[(mh) * 4 + mi][(nh) * 2 + ni] = __builtin_amdgcn_mfma_f32_16x16x32_bf16( \
              af[mi][ks], bfq[ni][ks], acc[(mh) * 4 + mi][(nh) * 2 + ni], 0, 0, 0);    \
    __builtin_amdgcn_s_setprio(0);
  #define BAR                                                                          \
    asm volatile("" ::: "memory");                                                     \
    __builtin_amdgcn_s_barrier();                                                      \
    asm volatile("" ::: "memory");

  STAGEA(0, 0, 0); STAGEA(0, 0, 1);
  STAGEB(0, 0, 0); STAGEB(0, 0, 1);
  asm volatile("s_waitcnt vmcnt(0) lgkmcnt(0)" ::: "memory");
  __builtin_amdgcn_s_barrier();
  asm volatile("" ::: "memory");

  #pragma unroll 1
  for (int t = 0; t < 7; ++t) {
    const int cur = t & 1, nxt = cur ^ 1;
    bf16x8 af[4][2], bfq[2][2];
    READ_A(0, cur); READ_B(0, cur);
    STAGEA(nxt, t + 1, 0);
    STAGEB(nxt, t + 1, 0);
    BAR; MFMAQ(0, 0); BAR;
    READ_B(1, cur);
    STAGEA(nxt, t + 1, 1);
    STAGEB(nxt, t + 1, 1);
    BAR; MFMAQ(0, 1); BAR;
    READ_A(1, cur); READ_B(0, cur);
    BAR; MFMAQ(1, 0); BAR;
    READ_B(1, cur);
    BAR; MFMAQ(1, 1);
    asm volatile("s_waitcnt vmcnt(0) lgkmcnt(0)" ::: "memory");
    BAR;
  }
  {
    bf16x8 af[4][2], bfq[2][2];
    READ_A(0, 1); READ_B(0, 1);
    BAR; MFMAQ(0, 0); BAR;
    READ_B(1, 1);
    BAR; MFMAQ(0, 1); BAR;
    READ_A(1, 1); READ_B(0, 1);
    BAR; MFMAQ(1, 0); BAR;
    READ_B(1, 1);
    BAR; MFMAQ(1, 1);
  }

  #undef STAGEA
  #undef STAGEB
  #undef READ_A
  #undef READ_B
  #undef MFMAQ
  #undef BAR

  float fv[4], vv[4];
  #pragma unroll
  for (int nf = 0; nf < 4; ++nf) {
    int col = half * 256 + wc * 64 + nf * 16 + lr;
    fv[nf] = first[b * NU + col];
    vv[nf] = V[col];
  }
  #pragma unroll
  for (int mf = 0; mf < 8; ++mf) {
    f32x4 p;
    #pragma unroll
    for (int r = 0; r < 4; ++r) {
      float s = 0.f;
      #pragma unroll
      for (int nf = 0; nf < 4; ++nf)
        s += vv[nf] * fast_tanh(fv[nf] + acc[mf][nf][r]);
      p[r] = s;
    }
    #pragma unroll
    for (int m = 1; m < 16; m <<= 1) {
      #pragma unroll
      for (int r = 0; r < 4; ++r) p[r] += __shfl_xor(p[r], m, 64);
    }
    if (lr == 0) {
      const int rbase = rowbase + wr * 128 + mf * 16 + hi2 * 4;
      #pragma unroll
      for (int r = 0; r < 4; ++r) atomicAdd(&s0[rbase + r], p[r]);
    }
  }
}

// ---------- fallback main (exact R17 champion, reg-staged A) ----------
__global__ __launch_bounds__(512, 2) void attn8(
    const float* __restrict__ h,
    const short* __restrict__ WtSw,
    const float* __restrict__ first,
    const float* __restrict__ V,
    float* __restrict__ s0)
{
  __shared__ short Alds[2][256 * 64];
  __shared__ short Blds[2][256 * 64];

  const int tid  = threadIdx.x;
  const int lane = tid & 63;
  const int w    = tid >> 6;
  const int wr   = w >> 2, wc = w & 3;
  const int lr   = lane & 15, hi2 = lane >> 4;

  const int bid = blockIdx.x;
  const int lb  = (bid & 7) * 64 + (bid >> 3);
  const int panel = lb >> 1, half = lb & 1;
  const int rowbase = panel * 256;
  const int b = panel >> 3;

  const float* hstage = h + (size_t)(rowbase + (tid >> 2)) * NU + (tid & 3) * 16;
  const int rr = tid >> 2, u0 = (tid & 3) * 2;
  const int wby0 = rr * 128 + ((u0 ^ (rr & 7)) << 4);
  const int wby1 = rr * 128 + (((u0 | 1) ^ (rr & 7)) << 4);
  const short* wsrc = WtSw + (size_t)(half * 256 + w * 8 + (lane >> 3)) * NU + (lane & 7) * 8;

  int abase[8], bbase[4], s16[2];
  #pragma unroll
  for (int j = 0; j < 8; ++j) abase[j] = (wr * 128 + j * 16 + lr) * 128;
  #pragma unroll
  for (int j = 0; j < 4; ++j) bbase[j] = (wc * 64 + j * 16 + lr) * 128;
  #pragma unroll
  for (int ks = 0; ks < 2; ++ks) s16[ks] = ((ks * 4 + hi2) ^ (lr & 7)) << 4;

  f32x4 acc[8][4];
  #pragma unroll
  for (int mf = 0; mf < 8; ++mf)
    #pragma unroll
    for (int nf = 0; nf < 4; ++nf)
      acc[mf][nf] = (f32x4){0.f, 0.f, 0.f, 0.f};

  float4 ga0, ga1, ga2, ga3;
  float4 gb0, gb1, gb2, gb3;

  #define STAGEB(nxt, t1, bh)                                                          \
    {                                                                                  \
      _Pragma("unroll")                                                                \
      for (int i = 0; i < 2; ++i)                                                      \
        __builtin_amdgcn_global_load_lds(                                              \
            (const __attribute__((address_space(1))) unsigned*)                        \
                (wsrc + (size_t)((bh) * 128 + i * 64) * NU + (t1) * 64),               \
            (__attribute__((address_space(3))) unsigned*)                              \
                (&Blds[nxt][(bh) * 8192 + i * 4096 + w * 512]), 16, 0, 0);             \
    }
  #define ISSA(G0, G1, G2, G3, t1, ah)                                                 \
    {                                                                                  \
      const float* p = hstage + (size_t)(ah) * 128 * NU + (t1) * 64;                   \
      G0 = *reinterpret_cast<const float4*>(p + 0);                                    \
      G1 = *reinterpret_cast<const float4*>(p + 4);                                    \
      G2 = *reinterpret_cast<const float4*>(p + 8);                                    \
      G3 = *reinterpret_cast<const float4*>(p + 12);                                   \
    }
  #define CVTW(nxt, ah, G0, G1, G2, G3)                                                \
    {                                                                                  \
      char* base = reinterpret_cast<char*>(&Alds[nxt][0]) + (ah) * 16384;              \
      uint4 ua, ub;                                                                    \
      ua.x = pk2(G0.x, G0.y); ua.y = pk2(G0.z, G0.w);                                  \
      ua.z = pk2(G1.x, G1.y); ua.w = pk2(G1.z, G1.w);                                  \
      ub.x = pk2(G2.x, G2.y); ub.y = pk2(G2.z, G2.w);                                  \
      ub.z = pk2(G3.x, G3.y); ub.w = pk2(G3.z, G3.w);                                  \
      *reinterpret_cast<uint4*>(base + wby0) = ua;                                     \
      *reinterpret_cast<uint4*>(base + wby1) = ub;                                     \
    }
  #define READ_A(mh, cur)                                                              \
    _Pragma("unroll")                                                                  \
    for (int mi = 0; mi < 4; ++mi)                                                     \
      _Pragma("unroll")                                                                \
      for (int ks = 0; ks < 2; ++ks)                                                   \
        af[mi][ks] = *reinterpret_cast<const bf16x8*>(                                 \
            reinterpret_cast<const char*>(&Alds[cur][0]) + abase[(mh) * 4 + mi] + s16[ks]);
  #define READ_B(nh, cur)                                                              \
    _Pragma("unroll")                                                                  \
    for (int ni = 0; ni < 2; ++ni)                                                     \
      _Pragma("unroll")                                                                \
      for (int ks = 0; ks < 2; ++ks)                                                   \
        bfq[ni][ks] = *reinterpret_cast<const bf16x8*>(                                \
            reinterpret_cast<const char*>(&Blds[cur][0]) + bbase[(nh) * 2 + ni] + s16[ks]);
  #define MFMAQ(mh, nh)                                                                \
    __builtin_amdgcn_s_setprio(1);                                                     \
    _Pragma("unroll")                                                                  \
    for (int ks = 0; ks < 2; ++ks)                                                     \
      _Pragma("unroll")                                                                \
      for (int mi = 0; mi < 4; ++mi)                                                   \
        _Pragma("unroll")                                                              \
        for (int ni = 0; ni < 2; ++ni)                                                 \
          acc[(mh) * 4 + mi][(nh) * 2 + ni] = __builtin_amdgcn_mfma_f32_16x16x32_bf16( \
              af[mi][ks], bfq[ni][ks], acc[(mh) * 4 + mi][(nh) * 2 + ni], 0, 0, 0);    \
    __builtin_amdgcn_s_setprio(0);
  #define BAR                                                                          \
    asm volatile("" ::: "memory");                                                     \
    __builtin_amdgcn_s_barrier();                                                      \
    asm volatile("" ::: "memory");

  STAGEB(0, 0, 0); STAGEB(0, 0, 1);
  ISSA(ga0, ga1, ga2, ga3, 0, 0);
  CVTW(0, 0, ga0, ga1, ga2, ga3);
  ISSA(gb0, gb1, gb2, gb3, 0, 1);
  CVTW(0, 1, gb0, gb1, gb2, gb3);
  asm volatile("s_waitcnt vmcnt(0) lgkmcnt(0)" ::: "memory");
  __builtin_amdgcn_s_barrier();
  asm volatile("" ::: "memory");

  #pragma unroll 1
  for (int t = 0; t < 7; ++t) {
    const int cur = t & 1, nxt = cur ^ 1;
    bf16x8 af[4][2], bfq[2][2];
    READ_A(0, cur); READ_B(0, cur);
    STAGEB(nxt, t + 1, 0);
    ISSA(ga0, ga1, ga2, ga3, t + 1, 0);
    BAR; MFMAQ(0, 0); BAR;
    READ_B(1, cur);
    STAGEB(nxt, t + 1, 1);
    ISSA(gb0, gb1, gb2, gb3, t + 1, 1);
    BAR; MFMAQ(0, 1); BAR;
    READ_A(1, cur); READ_B(0, cur);
    CVTW(nxt, 0, ga0, ga1, ga2, ga3);
    BAR; MFMAQ(1, 0); BAR;
    READ_B(1, cur);
    CVTW(nxt, 1, gb0, gb1, gb2, gb3);
    BAR; MFMAQ(1, 1);
    asm volatile("s_waitcnt vmcnt(0) lgkmcnt(0)" ::: "memory");
    BAR;
  }
  {
    bf16x8 af[4][2], bfq[2][2];
    READ_A(0, 1); READ_B(0, 1);
    BAR; MFMAQ(0, 0); BAR;
    READ_B(1, 1);
    BAR; MFMAQ(0, 1); BAR;
    READ_A(1, 1); READ_B(0, 1);
    BAR; MFMAQ(1, 0); BAR;
    READ_B(1, 1);
    BAR; MFMAQ(1, 1);
  }

  #undef STAGEB
  #undef ISSA
  #undef CVTW
  #undef READ_A
  #undef READ_B
  #undef MFMAQ
  #undef BAR

  float fv[4], vv[4];
  #pragma unroll
  for (int nf = 0; nf < 4; ++nf) {
    int col = half * 256 + wc * 64 + nf * 16 + lr;
    fv[nf] = first[b * NU + col];
    vv[nf] = V[col];
  }
  #pragma unroll
  for (int mf = 0; mf < 8; ++mf) {
    f32x4 p;
    #pragma unroll
    for (int r = 0; r < 4; ++r) {
      float s = 0.f;
      #pragma unroll
      for (int nf = 0; nf < 4; ++nf)
        s += vv[nf] * fast_tanh(fv[nf] + acc[mf][nf][r]);
      p[r] = s;
    }
    #pragma unroll
    for (int m = 1; m < 16; m <<= 1) {
      #pragma unroll
      for (int r = 0; r < 4; ++r) p[r] += __shfl_xor(p[r], m, 64);
    }
    if (lr == 0) {
      const int rbase = rowbase + wr * 128 + mf * 16 + hi2 * 4;
      #pragma unroll
      for (int r = 0; r < 4; ++r) atomicAdd(&s0[rbase + r], p[r]);
    }
  }
}

// ---------- softmax over S per batch (in-place in d_out) + context ----------
__global__ __launch_bounds__(256) void softmax_ctx(const float* __restrict__ sp,
                                                   float* __restrict__ out) {
  const int b = blockIdx.x;
  const int t = threadIdx.x;
  float* wgt = out + NBATCH * NU + (size_t)b * SEQ;
  __shared__ float red[4];

  float v[8];
  float mx = -1e30f;
  #pragma unroll
  for (int i = 0; i < 8; ++i) { v[i] = wgt[t + i * 256]; mx = fmaxf(mx, v[i]); }
  #pragma unroll
  for (int m = 1; m < 64; m <<= 1) mx = fmaxf(mx, __shfl_xor(mx, m, 64));
  if ((t & 63) == 0) red[t >> 6] = mx;
  __syncthreads();
  mx = fmaxf(fmaxf(red[0], red[1]), fmaxf(red[2], red[3]));
  __syncthreads();

  float se = 0.f;
  #pragma unroll
  for (int i = 0; i < 8; ++i) { v[i] = __expf(v[i] - mx); se += v[i]; }
  #pragma unroll
  for (int m = 1; m < 64; m <<= 1) se += __shfl_xor(se, m, 64);
  if ((t & 63) == 0) red[t >> 6] = se;
  __syncthreads();
  se = red[0] + red[1] + red[2] + red[3];
  __syncthreads();

  const float inv = 1.0f / se;
  float sw = 0.f;
  #pragma unroll
  for (int i = 0; i < 8; ++i) { float wi = v[i] * inv; wgt[t + i * 256] = wi; sw += wi; }
  #pragma unroll
  for (int m = 1; m < 64; m <<= 1) sw += __shfl_xor(sw, m, 64);
  if ((t & 63) == 0) red[t >> 6] = sw;
  __syncthreads();
  sw = red[0] + red[1] + red[2] + red[3];

  out[b * NU + t]       = sp[b * NU + t] * sw;
  out[b * NU + t + 256] = sp[b * NU + t + 256] * sw;
}

extern "C" void kernel_launch(void* const* d_in, const int* in_sizes, int n_in,
                              void* d_out, int out_size, void* d_ws, size_t ws_size,
                              hipStream_t stream) {
  (void)in_sizes; (void)n_in; (void)out_size;
  const float* s_prev = (const float*)d_in[0];
  const float* h      = (const float*)d_in[1];
  const float* Wk     = (const float*)d_in[2];
  const float* Wb     = (const float*)d_in[3];
  const float* Uk     = (const float*)d_in[4];
  const float* Ub     = (const float*)d_in[5];
  const float* Vk     = (const float*)d_in[6];
  // d_in[7] = V_bias: softmax-shift-invariant, does not affect outputs.

  float* out   = (float*)d_out;
  float* first = (float*)d_ws;                       // 64 KB
  short* WtSw  = (short*)((char*)d_ws + 65536);      // 512 KB
  short* hbf   = (short*)((char*)d_ws + (1 << 20));  // 64 MB (if ws permits)
  float* s0    = out + NBATCH * NU;

  const size_t need = (size_t)(1 << 20) + (size_t)65536 * NU * sizeof(short);
  const bool use_dma = (ws_size >= need);

  hipMemsetAsync(s0, 0, (size_t)NBATCH * SEQ * sizeof(float), stream);
  prep_cvt<<<use_dma ? 3136 : 1088, 256, 0, stream>>>(Wk, s_prev, Uk, Ub, Wb, h,
                                                      WtSw, first, hbf);
  if (use_dma) {
    attn8_dma<<<512, 512, 0, stream>>>(hbf, WtSw, first, Vk, s0);
  } else {
    attn8    <<<512, 512, 0, stream>>>(h, WtSw, first, Vk, s0);
  }
  softmax_ctx<<<32, 256, 0, stream>>>(s_prev, out);
}

// Round 22
// 111.760 us; speedup vs baseline: 1.2720x; 1.0095x over previous
//
#include <hip/hip_runtime.h>

#define NBATCH 32
#define SEQ    2048
#define NU     512

typedef __attribute__((ext_vector_type(8))) short bf16x8;
typedef __attribute__((ext_vector_type(4))) float f32x4;

__device__ __forceinline__ short bf16_rne(float f) {
  union { float f; unsigned u; } v; v.f = f;
  unsigned r = v.u + 0x7fffu + ((v.u >> 16) & 1u);
  return (short)(r >> 16);
}

__device__ __forceinline__ unsigned pk2(float lo, float hi) {
  return __builtin_amdgcn_perm(__float_as_uint(hi), __float_as_uint(lo), 0x07060302u);
}

__device__ __forceinline__ float fast_tanh(float x) {
  float ax = __builtin_fabsf(x);
  float t  = __expf(-2.0f * ax);
  float r  = (1.0f - t) / (1.0f + t);
  return x < 0.0f ? -r : r;
}

// ---------- fused prep + cvt ----------
// blocks 0..1023:    WtSw 8-unit-XOR pre-swizzled transpose (R17-verified)
// blocks 1024..1087: first[b][u] = s_prev[b]@U + U_bias + W_bias (verified)
// blocks 1088..3135: h fp32 -> hbf bf16 (lane-major, R21-verified layout), with
//   ALL 16 loads per wave hoisted into named regs before any store (asm fence) ->
//   16 outstanding loads/wave instead of 2 (R21's VGPR=32 serialization).
__global__ __launch_bounds__(256, 4) void prep_cvt(const float* __restrict__ W,
                                                   const float* __restrict__ sp,
                                                   const float* __restrict__ U,
                                                   const float* __restrict__ Ub,
                                                   const float* __restrict__ Wb,
                                                   const float* __restrict__ h,
                                                   short* __restrict__ WtSw,
                                                   float* __restrict__ first,
                                                   short* __restrict__ hbf) {
  __shared__ float srow[NU];
  if (blockIdx.x < 1024) {
    int idx = blockIdx.x * 256 + threadIdx.x;
    int C = idx >> 9, rem = idx & 511;
    int t = rem >> 6, up = (rem >> 3) & 7, e = rem & 7;
    int k = t * 64 + ((up ^ (C & 7)) << 3) + e;
    WtSw[idx] = bf16_rne(W[(size_t)k * NU + C]);
  } else if (blockIdx.x < 1088) {
    int blk = blockIdx.x - 1024;
    int b = blk >> 1, half = blk & 1, t = threadIdx.x;
    srow[t]       = sp[b * NU + t];
    srow[t + 256] = sp[b * NU + t + 256];
    __syncthreads();
    int col = half * 256 + t;
    float acc = Ub[col] + Wb[col];
    #pragma unroll 8
    for (int k = 0; k < NU; ++k) acc += srow[k] * U[(size_t)k * NU + col];
    first[b * NU + col] = acc;
  } else {
    // cvt: 2048 blocks x 4 waves; one wave per 8 rows; lane l owns 16B slot l*8
    const int gw = (blockIdx.x - 1088) * 4 + (threadIdx.x >> 6);
    const int l  = threadIdx.x & 63;
    const int tile = l >> 3, up = l & 7;
    const int r0 = gw * 8;
    float4 x[16];                       // statically indexed under full unroll -> regs
    #pragma unroll
    for (int i = 0; i < 8; ++i) {
      const int r = r0 + i;
      const int koff = tile * 64 + ((up ^ (r & 7)) << 3);
      const float* p = h + (size_t)r * NU + koff;
      x[2 * i]     = *reinterpret_cast<const float4*>(p);
      x[2 * i + 1] = *reinterpret_cast<const float4*>(p + 4);
    }
    asm volatile("" ::: "memory");      // loads may not sink below; stores may not rise
    #pragma unroll
    for (int i = 0; i < 8; ++i) {
      uint4 u;
      u.x = pk2(x[2 * i].x,     x[2 * i].y);
      u.y = pk2(x[2 * i].z,     x[2 * i].w);
      u.z = pk2(x[2 * i + 1].x, x[2 * i + 1].y);
      u.w = pk2(x[2 * i + 1].z, x[2 * i + 1].w);
      *reinterpret_cast<uint4*>(hbf + (size_t)(r0 + i) * NU + l * 8) = u;
    }
  }
}

// ---------- main (preferred): 8-phase, BOTH operands pure global_load_lds (R20/R21-verified) ----------
__global__ __launch_bounds__(512, 2) void attn8_dma(
    const short* __restrict__ hbf,    // pre-swizzled bf16 (65536 x 512)
    const short* __restrict__ WtSw,   // pre-swizzled (512 x 512) bf16
    const float* __restrict__ first,
    const float* __restrict__ V,
    float* __restrict__ s0)
{
  __shared__ short Alds[2][256 * 64];
  __shared__ short Blds[2][256 * 64];

  const int tid  = threadIdx.x;
  const int lane = tid & 63;
  const int w    = tid >> 6;
  const int wr   = w >> 2, wc = w & 3;
  const int lr   = lane & 15, hi2 = lane >> 4;

  const int bid = blockIdx.x;
  const int lb  = (bid & 7) * 64 + (bid >> 3);
  const int panel = lb >> 1, half = lb & 1;
  const int rowbase = panel * 256;
  const int b = panel >> 3;

  const short* asrc = hbf + (size_t)(rowbase + w * 32 + (lane >> 3)) * NU + (lane & 7) * 8;
  const short* wsrc = WtSw + (size_t)(half * 256 + w * 8 + (lane >> 3)) * NU + (lane & 7) * 8;

  #define STAGEA(nxt, t1, i2)                                                          \
    {                                                                                  \
      _Pragma("unroll")                                                                \
      for (int i = (i2) * 2; i < (i2) * 2 + 2; ++i)                                    \
        __builtin_amdgcn_global_load_lds(                                              \
            (const __attribute__((address_space(1))) unsigned*)                        \
                (asrc + (size_t)(i * 8) * NU + (t1) * 64),                             \
            (__attribute__((address_space(3))) unsigned*)                              \
                (&Alds[nxt][(w * 4 + i) * 512]), 16, 0, 0);                            \
    }
  #define STAGEB(nxt, t1, bh)                                                          \
    {                                                                                  \
      _Pragma("unroll")                                                                \
      for (int i = 0; i < 2; ++i)                                                      \
        __builtin_amdgcn_global_load_lds(                                              \
            (const __attribute__((address_space(1))) unsigned*)                        \
                (wsrc + (size_t)((bh) * 128 + i * 64) * NU + (t1) * 64),               \
            (__attribute__((address_space(3))) unsigned*)                              \
                (&Blds[nxt][(bh) * 8192 + i * 4096 + w * 512]), 16, 0, 0);             \
    }

  int abase[8], bbase[4], s16[2];
  #pragma unroll
  for (int j = 0; j < 8; ++j) abase[j] = (wr * 128 + j * 16 + lr) * 128;
  #pragma unroll
  for (int j = 0; j < 4; ++j) bbase[j] = (wc * 64 + j * 16 + lr) * 128;
  #pragma unroll
  for (int ks = 0; ks < 2; ++ks) s16[ks] = ((ks * 4 + hi2) ^ (lr & 7)) << 4;

  f32x4 acc[8][4];
  #pragma unroll
  for (int mf = 0; mf < 8; ++mf)
    #pragma unroll
    for (int nf = 0; nf < 4; ++nf)
      acc[mf][nf] = (f32x4){0.f, 0.f, 0.f, 0.f};

  #define READ_A(mh, cur)                                                              \
    _Pragma("unroll")                                                                  \
    for (int mi = 0; mi < 4; ++mi)                                                     \
      _Pragma("unroll")                                                                \
      for (int ks = 0; ks < 2; ++ks)                                                   \
        af[mi][ks] = *reinterpret_cast<const bf16x8*>(                                 \
            reinterpret_cast<const char*>(&Alds[cur][0]) + abase[(mh) * 4 + mi] + s16[ks]);
  #define READ_B(nh, cur)                                                              \
    _Pragma("unroll")                                                                  \
    for (int ni = 0; ni < 2; ++ni)                                                     \
      _Pragma("unroll")                                                                \
      for (int ks = 0; ks < 2; ++ks)                                                   \
        bfq[ni][ks] = *reinterpret_cast<const bf16x8*>(                                \
            reinterpret_cast<const char*>(&Blds[cur][0]) + bbase[(nh) * 2 + ni] + s16[ks]);
  #define MFMAQ(mh, nh)                                                                \
    __builtin_amdgcn_s_setprio(1);                                                     \
    _Pragma("unroll")                                                                  \
    for (int ks = 0; ks < 2; ++ks)                                                     \
      _Pragma("unroll")                                                                \
      for (int mi = 0; mi < 4; ++mi)                                                   \
        _Pragma("unroll")                                                              \
        for (int ni = 0; ni < 2; ++ni)                                                 \
          acc[(mh) * 4 + mi][(nh) * 2 + ni] = __builtin_amdgcn_mfma_f32_16x16x32_bf16( \
              af[mi][ks], bfq[ni][ks], acc[(mh) * 4 + mi][(nh) * 2 + ni], 0, 0, 0);    \
    __builtin_amdgcn_s_setprio(0);
  #define BAR                                                                          \
    asm volatile("" ::: "memory");                                                     \
    __builtin_amdgcn_s_barrier();                                                      \
    asm volatile("" ::: "memory");

  STAGEA(0, 0, 0); STAGEA(0, 0, 1);
  STAGEB(0, 0, 0); STAGEB(0, 0, 1);
  asm volatile("s_waitcnt vmcnt(0) lgkmcnt(0)" ::: "memory");
  __builtin_amdgcn_s_barrier();
  asm volatile("" ::: "memory");

  #pragma unroll 1
  for (int t = 0; t < 7; ++t) {
    const int cur = t & 1, nxt = cur ^ 1;
    bf16x8 af[4][2], bfq[2][2];
    READ_A(0, cur); READ_B(0, cur);
    STAGEA(nxt, t + 1, 0);
    STAGEB(nxt, t + 1, 0);
    BAR; MFMAQ(0, 0); BAR;
    READ_B(1, cur);
    STAGEA(nxt, t + 1, 1);
    STAGEB(nxt, t + 1, 1);
    BAR; MFMAQ(0, 1); BAR;
    READ_A(1, cur); READ_B(0, cur);
    BAR; MFMAQ(1, 0); BAR;
    READ_B(1, cur);
    BAR; MFMAQ(1, 1);
    asm volatile("s_waitcnt vmcnt(0) lgkmcnt(0)" ::: "memory");
    BAR;
  }
  {
    bf16x8 af[4][2], bfq[2][2];
    READ_A(0, 1); READ_B(0, 1);
    BAR; MFMAQ(0, 0); BAR;
    READ_B(1, 1);
    BAR; MFMAQ(0, 1); BAR;
    READ_A(1, 1); READ_B(0, 1);
    BAR; MFMAQ(1, 0); BAR;
    READ_B(1, 1);
    BAR; MFMAQ(1, 1);
  }

  #undef STAGEA
  #undef STAGEB
  #undef READ_A
  #undef READ_B
  #undef MFMAQ
  #undef BAR

  float fv[4], vv[4];
  #pragma unroll
  for (int nf = 0; nf < 4; ++nf) {
    int col = half * 256 + wc * 64 + nf * 16 + lr;
    fv[nf] = first[b * NU + col];
    vv[nf] = V[col];
  }
  #pragma unroll
  for (int mf = 0; mf < 8; ++mf) {
    f32x4 p;
    #pragma unroll
    for (int r = 0; r < 4; ++r) {
      float s = 0.f;
      #pragma unroll
      for (int nf = 0; nf < 4; ++nf)
        s += vv[nf] * fast_tanh(fv[nf] + acc[mf][nf][r]);
      p[r] = s;
    }
    #pragma unroll
    for (int m = 1; m < 16; m <<= 1) {
      #pragma unroll
      for (int r = 0; r < 4; ++r) p[r] += __shfl_xor(p[r], m, 64);
    }
    if (lr == 0) {
      const int rbase = rowbase + wr * 128 + mf * 16 + hi2 * 4;
      #pragma unroll
      for (int r = 0; r < 4; ++r) atomicAdd(&s0[rbase + r], p[r]);
    }
  }
}

// ---------- fallback main (exact R17 champion, reg-staged A) ----------
__global__ __launch_bounds__(512, 2) void attn8(
    const float* __restrict__ h,
    const short* __restrict__ WtSw,
    const float* __restrict__ first,
    const float* __restrict__ V,
    float* __restrict__ s0)
{
  __shared__ short Alds[2][256 * 64];
  __shared__ short Blds[2][256 * 64];

  const int tid  = threadIdx.x;
  const int lane = tid & 63;
  const int w    = tid >> 6;
  const int wr   = w >> 2, wc = w & 3;
  const int lr   = lane & 15, hi2 = lane >> 4;

  const int bid = blockIdx.x;
  const int lb  = (bid & 7) * 64 + (bid >> 3);
  const int panel = lb >> 1, half = lb & 1;
  const int rowbase = panel * 256;
  const int b = panel >> 3;

  const float* hstage = h + (size_t)(rowbase + (tid >> 2)) * NU + (tid & 3) * 16;
  const int rr = tid >> 2, u0 = (tid & 3) * 2;
  const int wby0 = rr * 128 + ((u0 ^ (rr & 7)) << 4);
  const int wby1 = rr * 128 + (((u0 | 1) ^ (rr & 7)) << 4);
  const short* wsrc = WtSw + (size_t)(half * 256 + w * 8 + (lane >> 3)) * NU + (lane & 7) * 8;

  int abase[8], bbase[4], s16[2];
  #pragma unroll
  for (int j = 0; j < 8; ++j) abase[j] = (wr * 128 + j * 16 + lr) * 128;
  #pragma unroll
  for (int j = 0; j < 4; ++j) bbase[j] = (wc * 64 + j * 16 + lr) * 128;
  #pragma unroll
  for (int ks = 0; ks < 2; ++ks) s16[ks] = ((ks * 4 + hi2) ^ (lr & 7)) << 4;

  f32x4 acc[8][4];
  #pragma unroll
  for (int mf = 0; mf < 8; ++mf)
    #pragma unroll
    for (int nf = 0; nf < 4; ++nf)
      acc[mf][nf] = (f32x4){0.f, 0.f, 0.f, 0.f};

  float4 ga0, ga1, ga2, ga3;
  float4 gb0, gb1, gb2, gb3;

  #define STAGEB(nxt, t1, bh)                                                          \
    {                                                                                  \
      _Pragma("unroll")                                                                \
      for (int i = 0; i < 2; ++i)                                                      \
        __builtin_amdgcn_global_load_lds(                                              \
            (const __attribute__((address_space(1))) unsigned*)                        \
                (wsrc + (size_t)((bh) * 128 + i * 64) * NU + (t1) * 64),               \
            (__attribute__((address_space(3))) unsigned*)                              \
                (&Blds[nxt][(bh) * 8192 + i * 4096 + w * 512]), 16, 0, 0);             \
    }
  #define ISSA(G0, G1, G2, G3, t1, ah)                                                 \
    {                                                                                  \
      const float* p = hstage + (size_t)(ah) * 128 * NU + (t1) * 64;                   \
      G0 = *reinterpret_cast<const float4*>(p + 0);                                    \
      G1 = *reinterpret_cast<const float4*>(p + 4);                                    \
      G2 = *reinterpret_cast<const float4*>(p + 8);                                    \
      G3 = *reinterpret_cast<const float4*>(p + 12);                                   \
    }
  #define CVTW(nxt, ah, G0, G1, G2, G3)                                                \
    {                                                                                  \
      char* base = reinterpret_cast<char*>(&Alds[nxt][0]) + (ah) * 16384;              \
      uint4 ua, ub;                                                                    \
      ua.x = pk2(G0.x, G0.y); ua.y = pk2(G0.z, G0.w);                                  \
      ua.z = pk2(G1.x, G1.y); ua.w = pk2(G1.z, G1.w);                                  \
      ub.x = pk2(G2.x, G2.y); ub.y = pk2(G2.z, G2.w);                                  \
      ub.z = pk2(G3.x, G3.y); ub.w = pk2(G3.z, G3.w);                                  \
      *reinterpret_cast<uint4*>(base + wby0) = ua;                                     \
      *reinterpret_cast<uint4*>(base + wby1) = ub;                                     \
    }
  #define READ_A(mh, cur)                                                              \
    _Pragma("unroll")                                                                  \
    for (int mi = 0; mi < 4; ++mi)                                                     \
      _Pragma("unroll")                                                                \
      for (int ks = 0; ks < 2; ++ks)                                                   \
        af[mi][ks] = *reinterpret_cast<const bf16x8*>(                                 \
            reinterpret_cast<const char*>(&Alds[cur][0]) + abase[(mh) * 4 + mi] + s16[ks]);
  #define READ_B(nh, cur)                                                              \
    _Pragma("unroll")                                                                  \
    for (int ni = 0; ni < 2; ++ni)                                                     \
      _Pragma("unroll")                                                                \
      for (int ks = 0; ks < 2; ++ks)                                                   \
        bfq[ni][ks] = *reinterpret_cast<const bf16x8*>(                                \
            reinterpret_cast<const char*>(&Blds[cur][0]) + bbase[(nh) * 2 + ni] + s16[ks]);
  #define MFMAQ(mh, nh)                                                                \
    __builtin_amdgcn_s_setprio(1);                                                     \
    _Pragma("unroll")                                                                  \
    for (int ks = 0; ks < 2; ++ks)                                                     \
      _Pragma("unroll")                                                                \
      for (int mi = 0; mi < 4; ++mi)                                                   \
        _Pragma("unroll")                                                              \
        for (int ni = 0; ni < 2; ++ni)                                                 \
          acc[(mh) * 4 + mi][(nh) * 2 + ni] = __builtin_amdgcn_mfma_f32_16x16x32_bf16( \
              af[mi][ks], bfq[ni][ks], acc[(mh) * 4 + mi][(nh) * 2 + ni], 0, 0, 0);    \
    __builtin_amdgcn_s_setprio(0);
  #define BAR                                                                          \
    asm volatile("" ::: "memory");                                                     \
    __builtin_amdgcn_s_barrier();                                                      \
    asm volatile("" ::: "memory");

  STAGEB(0, 0, 0); STAGEB(0, 0, 1);
  ISSA(ga0, ga1, ga2, ga3, 0, 0);
  CVTW(0, 0, ga0, ga1, ga2, ga3);
  ISSA(gb0, gb1, gb2, gb3, 0, 1);
  CVTW(0, 1, gb0, gb1, gb2, gb3);
  asm volatile("s_waitcnt vmcnt(0) lgkmcnt(0)" ::: "memory");
  __builtin_amdgcn_s_barrier();
  asm volatile("" ::: "memory");

  #pragma unroll 1
  for (int t = 0; t < 7; ++t) {
    const int cur = t & 1, nxt = cur ^ 1;
    bf16x8 af[4][2], bfq[2][2];
    READ_A(0, cur); READ_B(0, cur);
    STAGEB(nxt, t + 1, 0);
    ISSA(ga0, ga1, ga2, ga3, t + 1, 0);
    BAR; MFMAQ(0, 0); BAR;
    READ_B(1, cur);
    STAGEB(nxt, t + 1, 1);
    ISSA(gb0, gb1, gb2, gb3, t + 1, 1);
    BAR; MFMAQ(0, 1); BAR;
    READ_A(1, cur); READ_B(0, cur);
    CVTW(nxt, 0, ga0, ga1, ga2, ga3);
    BAR; MFMAQ(1, 0); BAR;
    READ_B(1, cur);
    CVTW(nxt, 1, gb0, gb1, gb2, gb3);
    BAR; MFMAQ(1, 1);
    asm volatile("s_waitcnt vmcnt(0) lgkmcnt(0)" ::: "memory");
    BAR;
  }
  {
    bf16x8 af[4][2], bfq[2][2];
    READ_A(0, 1); READ_B(0, 1);
    BAR; MFMAQ(0, 0); BAR;
    READ_B(1, 1);
    BAR; MFMAQ(0, 1); BAR;
    READ_A(1, 1); READ_B(0, 1);
    BAR; MFMAQ(1, 0); BAR;
    READ_B(1, 1);
    BAR; MFMAQ(1, 1);
  }

  #undef STAGEB
  #undef ISSA
  #undef CVTW
  #undef READ_A
  #undef READ_B
  #undef MFMAQ
  #undef BAR

  float fv[4], vv[4];
  #pragma unroll
  for (int nf = 0; nf < 4; ++nf) {
    int col = half * 256 + wc * 64 + nf * 16 + lr;
    fv[nf] = first[b * NU + col];
    vv[nf] = V[col];
  }
  #pragma unroll
  for (int mf = 0; mf < 8; ++mf) {
    f32x4 p;
    #pragma unroll
    for (int r = 0; r < 4; ++r) {
      float s = 0.f;
      #pragma unroll
      for (int nf = 0; nf < 4; ++nf)
        s += vv[nf] * fast_tanh(fv[nf] + acc[mf][nf][r]);
      p[r] = s;
    }
    #pragma unroll
    for (int m = 1; m < 16; m <<= 1) {
      #pragma unroll
      for (int r = 0; r < 4; ++r) p[r] += __shfl_xor(p[r], m, 64);
    }
    if (lr == 0) {
      const int rbase = rowbase + wr * 128 + mf * 16 + hi2 * 4;
      #pragma unroll
      for (int r = 0; r < 4; ++r) atomicAdd(&s0[rbase + r], p[r]);
    }
  }
}

// ---------- softmax over S per batch (in-place in d_out) + context ----------
__global__ __launch_bounds__(256) void softmax_ctx(const float* __restrict__ sp,
                                                   float* __restrict__ out) {
  const int b = blockIdx.x;
  const int t = threadIdx.x;
  float* wgt = out + NBATCH * NU + (size_t)b * SEQ;
  __shared__ float red[4];

  float v[8];
  float mx = -1e30f;
  #pragma unroll
  for (int i = 0; i < 8; ++i) { v[i] = wgt[t + i * 256]; mx = fmaxf(mx, v[i]); }
  #pragma unroll
  for (int m = 1; m < 64; m <<= 1) mx = fmaxf(mx, __shfl_xor(mx, m, 64));
  if ((t & 63) == 0) red[t >> 6] = mx;
  __syncthreads();
  mx = fmaxf(fmaxf(red[0], red[1]), fmaxf(red[2], red[3]));
  __syncthreads();

  float se = 0.f;
  #pragma unroll
  for (int i = 0; i < 8; ++i) { v[i] = __expf(v[i] - mx); se += v[i]; }
  #pragma unroll
  for (int m = 1; m < 64; m <<= 1) se += __shfl_xor(se, m, 64);
  if ((t & 63) == 0) red[t >> 6] = se;
  __syncthreads();
  se = red[0] + red[1] + red[2] + red[3];
  __syncthreads();

  const float inv = 1.0f / se;
  float sw = 0.f;
  #pragma unroll
  for (int i = 0; i < 8; ++i) { float wi = v[i] * inv; wgt[t + i * 256] = wi; sw += wi; }
  #pragma unroll
  for (int m = 1; m < 64; m <<= 1) sw += __shfl_xor(sw, m, 64);
  if ((t & 63) == 0) red[t >> 6] = sw;
  __syncthreads();
  sw = red[0] + red[1] + red[2] + red[3];

  out[b * NU + t]       = sp[b * NU + t] * sw;
  out[b * NU + t + 256] = sp[b * NU + t + 256] * sw;
}

extern "C" void kernel_launch(void* const* d_in, const int* in_sizes, int n_in,
                              void* d_out, int out_size, void* d_ws, size_t ws_size,
                              hipStream_t stream) {
  (void)in_sizes; (void)n_in; (void)out_size;
  const float* s_prev = (const float*)d_in[0];
  const float* h      = (const float*)d_in[1];
  const float* Wk     = (const float*)d_in[2];
  const float* Wb     = (const float*)d_in[3];
  const float* Uk     = (const float*)d_in[4];
  const float* Ub     = (const float*)d_in[5];
  const float* Vk     = (const float*)d_in[6];
  // d_in[7] = V_bias: softmax-shift-invariant, does not affect outputs.

  float* out   = (float*)d_out;
  float* first = (float*)d_ws;                       // 64 KB
  short* WtSw  = (short*)((char*)d_ws + 65536);      // 512 KB
  short* hbf   = (short*)((char*)d_ws + (1 << 20));  // 64 MB (if ws permits)
  float* s0    = out + NBATCH * NU;

  const size_t need = (size_t)(1 << 20) + (size_t)65536 * NU * sizeof(short);
  const bool use_dma = (ws_size >= need);

  hipMemsetAsync(s0, 0, (size_t)NBATCH * SEQ * sizeof(float), stream);
  prep_cvt<<<use_dma ? 3136 : 1088, 256, 0, stream>>>(Wk, s_prev, Uk, Ub, Wb, h,
                                                      WtSw, first, hbf);
  if (use_dma) {
    attn8_dma<<<512, 512, 0, stream>>>(hbf, WtSw, first, Vk, s0);
  } else {
    attn8    <<<512, 512, 0, stream>>>(h, WtSw, first, Vk, s0);
  }
  softmax_ctx<<<32, 256, 0, stream>>>(s_prev, out);
}